// Round 8
// baseline (198.064 us; speedup 1.0000x reference)
//
#include <hip/hip_runtime.h>

// LocalPredictor: 3x3 conv (32->128, center masked) + ReLU + 1x1 conv (128->32)
// B=8, k=32, H=W=256, HID=128. fp32 in/out (values bf16-exact) -> bf16 MFMA.
// v8 = v7 with the ZSLOT overflow fixed (was 2672; right-halo slot x=65 needs
// zsw(65)+3*8+8 = 2696 -> halo writes corrupted adjacent rows / h_lds).
//  - swapped-operand GEMM1 (acc = h^T): h-epilogue 8x ds_write_b64
//  - z_lds swizzle zsw(x)=x*40+(x&~7): conflict-free commit writes
//  - w1 fragments (tap-invariant) hoisted to registers; waves_per_eu(3,4)

#define KC 32
#define HH 256
#define WW 256
#define HID 128
#define YS 8
#define ZSLOT 2696   // per-row slot: zsw(65)+24+8 = 2696 ushorts (5392 B, 16B-aligned)

typedef __attribute__((ext_vector_type(8))) short short8;
typedef __attribute__((ext_vector_type(4))) short short4v;
typedef __attribute__((ext_vector_type(4))) float f32x4;

// LDS-visibility barrier WITHOUT vmcnt drain: global loads/stores stay in flight.
#define BARRIER() asm volatile("s_waitcnt lgkmcnt(0)\n\ts_barrier" ::: "memory")
#define SCHED_FENCE() asm volatile("" ::: "memory")

__device__ __forceinline__ int zsw(int x) { return x * 40 + (x & ~7); }

__device__ __forceinline__ unsigned short f2bf(float f) {
    union { float f; unsigned int i; } x; x.f = f;
    unsigned int r = x.i + 0x7FFFu + ((x.i >> 16) & 1u);  // RNE
    return (unsigned short)(r >> 16);
}

// pack 8 bf16-exact floats -> short8 (truncate = exact)
__device__ __forceinline__ short8 pack8(const float* v) {
    union { short8 s; unsigned int u[4]; } w;
    union { float f; unsigned int i; } uu[8];
#pragma unroll
    for (int j = 0; j < 8; ++j) uu[j].f = v[j];
#pragma unroll
    for (int k = 0; k < 4; ++k)
        w.u[k] = __builtin_amdgcn_perm(uu[2 * k + 1].i, uu[2 * k].i, 0x07060302u);
    return w.s;
}

// ws: w1t bf16[9*HID*KC] | w2t bf16[KC*HID].  w1t[p][d][c], c contiguous.
__global__ void prep_weights(const float* __restrict__ w1,
                             const float* __restrict__ w2,
                             unsigned short* __restrict__ w1t,
                             unsigned short* __restrict__ w2t) {
    int i = blockIdx.x * 256 + threadIdx.x;
    if (i < 9 * HID * KC) {
        int c = i & 31;
        int d = (i >> 5) & 127;
        int p = i >> 12;
        w1t[i] = f2bf(w1[d * (9 * KC) + c * 9 + p]);
    } else if (i < 9 * HID * KC + KC * HID) {
        int j = i - 9 * HID * KC;
        w2t[j] = f2bf(w2[j]);
    }
}

__global__ __attribute__((amdgpu_flat_work_group_size(256, 256), amdgpu_waves_per_eu(3, 4)))
void local_pred_kernel(
    const float* __restrict__ zg,
    const unsigned short* __restrict__ w1t,
    const float* __restrict__ b1g,
    const unsigned short* __restrict__ w2t,
    const float* __restrict__ b2g,
    float* __restrict__ outg)
{
    __shared__ __attribute__((aligned(16))) unsigned short z_lds[4 * ZSLOT];     // 21568 B
    __shared__ __attribute__((aligned(16))) unsigned short h_lds[64 * 136];      // 17408 B
    __shared__ __attribute__((aligned(16))) unsigned short halo_lds[7 * 2 * 32]; //   896 B

    const int tid  = threadIdx.x;
    const int bidx = blockIdx.x;
    const int x0 = (bidx & 3) << 6;
    const int y0 = ((bidx >> 2) & 31) * YS;
    const int b  = bidx >> 7;

    const int l = tid & 63;       // staging x-lane
    const int o = tid >> 6;       // staging c-octet

    const int wave = tid >> 6;
    const int lane = tid & 63;
    const int lr = lane & 15;
    const int lq = lane >> 4;

    const float* zb = zg + (size_t)b * KC * HH * WW;

    // ---------------- prologue: sequential fenced staging rounds ----------------
#pragma unroll
    for (int dy = 0; dy < 3; ++dy) {
        const int gy = y0 - 1 + dy;
        const bool ok = (unsigned)gy < (unsigned)HH;
        const float* p = zb + ((size_t)(o * 8) * HH + (ok ? gy : 0)) * WW + x0 + l;
        float t8[8];
#pragma unroll
        for (int j = 0; j < 8; ++j) t8[j] = ok ? p[(size_t)j * HH * WW] : 0.f;
        *(short8*)&z_lds[dy * ZSLOT + zsw(l + 1) + o * 8] = pack8(t8);
        SCHED_FENCE();
    }
    // near halo (rows y0-1..y0+1): tid<24 -> (side, c-octet, dy)
    {
        const int s = tid & 1, oc = (tid >> 1) & 3, dy = tid >> 3;
        const int gy = y0 - 1 + dy;
        const int gx = x0 - 1 + s * 65;
        const bool ok = (tid < 24) && ((unsigned)gy < (unsigned)HH) &&
                        ((unsigned)gx < (unsigned)WW);
        const float* q = zb + ((size_t)(oc * 8) * HH + (ok ? gy : 0)) * WW + (ok ? gx : 0);
        float t8[8];
#pragma unroll
        for (int j = 0; j < 8; ++j) t8[j] = ok ? q[(size_t)j * HH * WW] : 0.f;
        if (tid < 24)
            *(short8*)&z_lds[dy * ZSLOT + zsw(s * 65) + oc * 8] = pack8(t8);
        SCHED_FENCE();
    }
    // far halo (rows y0+2..y0+8): tid in [64,120) -> (side, c-octet, row)
    {
        const int fi = tid - 64;
        const int s = fi & 1, oc = (fi >> 1) & 3, fr = fi >> 3;
        const int gy = y0 + 2 + fr;
        const int gx = x0 - 1 + s * 65;
        const bool ok = (tid >= 64) && (tid < 120) && (gy < HH) &&
                        ((unsigned)gx < (unsigned)WW);
        const float* q = zb + ((size_t)(oc * 8) * HH + (ok ? gy : 0)) * WW + (ok ? gx : 0);
        float t8[8];
#pragma unroll
        for (int j = 0; j < 8; ++j) t8[j] = ok ? q[(size_t)j * HH * WW] : 0.f;
        if (tid >= 64 && tid < 120)
            *(short8*)&halo_lds[(fr * 2 + s) * 32 + oc * 8] = pack8(t8);
        SCHED_FENCE();
    }

    // hoisted constants: w1 A-frags (tap-invariant!), biases
    short8 w1f[8][2];   // [tap][dt]: A[d][k], d = wave*32+dt*16+lr, k = lq*8+j
    {
        const int tap_p[8] = {0, 1, 2, 3, 5, 6, 7, 8};
#pragma unroll
        for (int t = 0; t < 8; ++t)
#pragma unroll
            for (int dt = 0; dt < 2; ++dt)
                w1f[t][dt] = *(const short8*)
                    &w1t[tap_p[t] * (HID * KC) + (wave * 32 + dt * 16 + lr) * KC + lq * 8];
    }
    f32x4 bias1v[2];    // [dt]: b1[wave*32+dt*16+lq*4 + rr]
#pragma unroll
    for (int dt = 0; dt < 2; ++dt)
        bias1v[dt] = *(const f32x4*)&b1g[wave * 32 + dt * 16 + lq * 4];
    float bias2[2];
#pragma unroll
    for (int nt = 0; nt < 2; ++nt) bias2[nt] = b2g[nt * 16 + lr];

    BARRIER();

    const int tap_di[8] = {0, 0, 0, 1, 1, 2, 2, 2};
    const int tap_dj[8] = {0, 1, 2, 0, 2, 0, 1, 2};

    float mv8[8];   // distance-1 prefetch buffer

#pragma unroll
    for (int r = 0; r < YS; ++r) {
        const int y = y0 + r;
        const int S0 = r & 3, S1 = (r + 1) & 3, S2 = (r + 2) & 3, S3 = (r + 3) & 3;

        // ---------- issue prefetch: row y+2 (committed at end of this iter) ----------
        if (r < 7) {
            const int gy = y + 2;
            const bool ok = gy < HH;
            const float* p = zb + ((size_t)(o * 8) * HH + (ok ? gy : 0)) * WW + x0 + l;
#pragma unroll
            for (int j = 0; j < 8; ++j) mv8[j] = ok ? p[(size_t)j * HH * WW] : 0.f;
        }
        SCHED_FENCE();

        // ---------- GEMM1 (swapped): accT[dt][mt] = h^T tile [d=16][m=16] ----------
        f32x4 accT[2][4];
#pragma unroll
        for (int dt = 0; dt < 2; ++dt)
#pragma unroll
            for (int mt = 0; mt < 4; ++mt)
                accT[dt][mt] = (f32x4){0.f, 0.f, 0.f, 0.f};

        const int rowoff[3] = {S0 * ZSLOT, S1 * ZSLOT, S2 * ZSLOT};
#pragma unroll
        for (int t = 0; t < 8; ++t) {
            const int di = tap_di[t], dj = tap_dj[t];
            short8 bfr[4];  // B[k][m]: col m = mt*16+lr (+dj shift), k = lq*8+j
#pragma unroll
            for (int mt = 0; mt < 4; ++mt)
                bfr[mt] = *(const short8*)&z_lds[rowoff[di] + zsw(mt * 16 + lr + dj) + lq * 8];
#pragma unroll
            for (int dt = 0; dt < 2; ++dt)
#pragma unroll
                for (int mt = 0; mt < 4; ++mt)
                    accT[dt][mt] = __builtin_amdgcn_mfma_f32_16x16x32_bf16(
                        w1f[t][dt], bfr[mt], accT[dt][mt], 0, 0, 0);
        }

        // ---------- epilogue1: +b1, ReLU, bf16, b64 writes (4 consecutive d) ----------
        // D layout: row = d_local = lq*4+rr, col = m_local = lr
#pragma unroll
        for (int dt = 0; dt < 2; ++dt) {
#pragma unroll
            for (int mt = 0; mt < 4; ++mt) {
                unsigned int lo, hi;
                {
                    float v0 = accT[dt][mt][0] + bias1v[dt][0]; v0 = v0 > 0.f ? v0 : 0.f;
                    float v1 = accT[dt][mt][1] + bias1v[dt][1]; v1 = v1 > 0.f ? v1 : 0.f;
                    float v2 = accT[dt][mt][2] + bias1v[dt][2]; v2 = v2 > 0.f ? v2 : 0.f;
                    float v3 = accT[dt][mt][3] + bias1v[dt][3]; v3 = v3 > 0.f ? v3 : 0.f;
                    lo = (unsigned int)f2bf(v0) | ((unsigned int)f2bf(v1) << 16);
                    hi = (unsigned int)f2bf(v2) | ((unsigned int)f2bf(v3) << 16);
                }
                union { short4v s; unsigned int u[2]; } pk;
                pk.u[0] = lo; pk.u[1] = hi;
                const int m = mt * 16 + lr;
                const int d = wave * 32 + dt * 16 + lq * 4;
                *(short4v*)&h_lds[m * 136 + d] = pk.s;
            }
        }
        BARRIER();   // h ready; all waves' GEMM1 z-reads complete

        // ---------- GEMM2: M=64 px, N=32 out, K=128 (B from L1-hot w2t) ----------
        f32x4 acc2[2];
        acc2[0] = (f32x4){0.f, 0.f, 0.f, 0.f};
        acc2[1] = (f32x4){0.f, 0.f, 0.f, 0.f};
        const int m2 = wave * 16 + lr;
#pragma unroll
        for (int k4 = 0; k4 < 4; ++k4) {
            short8 afr = *(const short8*)&h_lds[m2 * 136 + k4 * 32 + lq * 8];
#pragma unroll
            for (int nt = 0; nt < 2; ++nt) {
                short8 bfr = *(const short8*)&w2t[(nt * 16 + lr) * HID + k4 * 32 + lq * 8];
                acc2[nt] = __builtin_amdgcn_mfma_f32_16x16x32_bf16(afr, bfr, acc2[nt], 0, 0, 0);
            }
        }

        // ---------- epilogue2: +b2, 16B coalesced stores ----------
#pragma unroll
        for (int nt = 0; nt < 2; ++nt) {
            const int kout = nt * 16 + lr;
            f32x4 pk;
#pragma unroll
            for (int rr = 0; rr < 4; ++rr) pk[rr] = acc2[nt][rr] + bias2[nt];
            const int mb = wave * 16 + lq * 4;
            const size_t off = ((size_t)(b * KC + kout) * HH + y) * WW + x0 + mb;
            *(f32x4*)&outg[off] = pk;
        }

        // ---------- commit prefetched row y+2 into slot S3 (swizzled, conflict-free) ----------
        if (r < 7) {
            *(short8*)&z_lds[S3 * ZSLOT + zsw(l + 1) + o * 8] = pack8(mv8);
            if (tid < 8) {
                const int side = tid & 1, oct = tid >> 1;
                short8 hv = *(const short8*)&halo_lds[(r * 2 + side) * 32 + oct * 8];
                *(short8*)&z_lds[S3 * ZSLOT + zsw(side * 65) + oct * 8] = hv;
            }
        }
        BARRIER();   // commit visible; h-reads done (h rewritten next iter)
    }
}

extern "C" void kernel_launch(void* const* d_in, const int* in_sizes, int n_in,
                              void* d_out, int out_size, void* d_ws, size_t ws_size,
                              hipStream_t stream)
{
    const float* z  = (const float*)d_in[0];
    const float* W1 = (const float*)d_in[1];
    const float* b1 = (const float*)d_in[2];
    const float* W2 = (const float*)d_in[3];
    const float* b2 = (const float*)d_in[4];
    float* out = (float*)d_out;
    unsigned short* w1t = (unsigned short*)d_ws;                // 73728 B
    unsigned short* w2t = (unsigned short*)d_ws + 9 * HID * KC; // + 8192 B

    hipLaunchKernelGGL(prep_weights, dim3(160), dim3(256), 0, stream, W1, W2, w1t, w2t);
    hipLaunchKernelGGL(local_pred_kernel, dim3(8 * 4 * (HH / YS)), dim3(256), 0, stream,
                       z, w1t, b1, w2t, b2, out);
}